// Round 3
// baseline (66.460 us; speedup 1.0000x reference)
//
#include <hip/hip_runtime.h>

#define BATCH 4
#define NPTS 8192
#define TOTAL_ROWS (2 * BATCH * NPTS)   // 65536 min-keys (dir0 rows + dir1 cols)

typedef __attribute__((ext_vector_type(8))) short bf16x8;
typedef __attribute__((ext_vector_type(4))) float f32x4;

// Monotone float<->uint key: unsigned ascending == float ascending.
__device__ __forceinline__ unsigned fkey(float f) {
    unsigned u = __float_as_uint(f);
    return (u & 0x80000000u) ? ~u : (u | 0x80000000u);
}
__device__ __forceinline__ float funkey(unsigned k) {
    return (k & 0x80000000u) ? __uint_as_float(k ^ 0x80000000u) : __uint_as_float(~k);
}
__device__ __forceinline__ unsigned short bf16rn(float f) {
    unsigned u = __float_as_uint(f);
    return (unsigned short)((u + 0x7FFFu + ((u >> 16) & 1u)) >> 16);
}
__device__ __forceinline__ float bf2f(unsigned short h) {
    return __uint_as_float(((unsigned)h) << 16);
}

// Feature K-slot pairing (A[k]*B[k] summed by MFMA):
//  k0-2 : (-2a)_h * b_h      k3-5 : (-2a)_l * b_h     k6-8 : (-2a)_h * b_l
//  k9-10: a2_h,a2_l * 1      k11-12: 1 * b2_h,b2_l    k13-15: 0
// => D[m,n] = a^2 + b^2 - 2 a.b  (drops only (-2a)_l*b_l ~ 2^-18)
__global__ __launch_bounds__(256) void prep_kernel(
    const float* __restrict__ tpl, const float* __restrict__ src,
    unsigned short* __restrict__ Afeat, unsigned short* __restrict__ Bfeat)
{
    const int gid = blockIdx.x * 256 + threadIdx.x;   // 0..65535
    const int which = gid >> 15;                       // 0: tpl (A-side), 1: src (B-side)
    const int idx = gid & 32767;                       // batch*NPTS + pt
    const float* p = (which ? src : tpl) + (size_t)idx * 3;
    const float x = p[0], y = p[1], z = p[2];
    const float n2 = fmaf(x, x, fmaf(y, y, z * z));
    const unsigned short n2h = bf16rn(n2);
    const unsigned short n2l = bf16rn(n2 - bf2f(n2h));
    const unsigned short ONE = 0x3F80;

    __attribute__((aligned(16))) unsigned short f[16];
    if (which == 0) {
        const float mx = -2.0f * x, my = -2.0f * y, mz = -2.0f * z;
        const unsigned short hx = bf16rn(mx), hy = bf16rn(my), hz = bf16rn(mz);
        const unsigned short lx = bf16rn(mx - bf2f(hx));
        const unsigned short ly = bf16rn(my - bf2f(hy));
        const unsigned short lz = bf16rn(mz - bf2f(hz));
        f[0]=hx; f[1]=hy; f[2]=hz; f[3]=lx; f[4]=ly; f[5]=lz;
        f[6]=hx; f[7]=hy; f[8]=hz; f[9]=n2h; f[10]=n2l; f[11]=ONE; f[12]=ONE;
        f[13]=0; f[14]=0; f[15]=0;
        unsigned short* o = Afeat + (size_t)idx * 16;
        *(float4*)&o[0] = *(float4*)&f[0];
        *(float4*)&o[8] = *(float4*)&f[8];
    } else {
        const unsigned short hx = bf16rn(x), hy = bf16rn(y), hz = bf16rn(z);
        const unsigned short lx = bf16rn(x - bf2f(hx));
        const unsigned short ly = bf16rn(y - bf2f(hy));
        const unsigned short lz = bf16rn(z - bf2f(hz));
        f[0]=hx; f[1]=hy; f[2]=hz; f[3]=hx; f[4]=hy; f[5]=hz;
        f[6]=lx; f[7]=ly; f[8]=lz; f[9]=ONE; f[10]=ONE; f[11]=n2h; f[12]=n2l;
        f[13]=0; f[14]=0; f[15]=0;
        unsigned short* o = Bfeat + (size_t)idx * 16;
        *(float4*)&o[0] = *(float4*)&f[0];
        *(float4*)&o[8] = *(float4*)&f[8];
    }
}

// Main kernel: per block = (a-slab 512 rows) x (b-slab 512 cols) x batch.
// 4 waves x 8 a-tiles each; B-slab features staged in LDS.
// One shared distance matrix serves BOTH chamfer directions:
//   row-min (tpl->src) accumulated in regs; col-min (src->tpl) per b-tile.
__global__ __launch_bounds__(256) void chamfer_mfma_kernel(
    const unsigned short* __restrict__ Afeat,
    const unsigned short* __restrict__ Bfeat,
    unsigned int* __restrict__ keys)
{
    __shared__ unsigned short sB[2 * 512 * 8];   // [oct][pt][8 slots], 16 KB

    const int aSlab = blockIdx.x;   // 0..15
    const int bSlab = blockIdx.y;   // 0..15
    const int batch = blockIdx.z;   // 0..3

    const int t     = threadIdx.x;
    const int w     = t >> 6;       // wave 0..3
    const int lane  = t & 63;
    const int col16 = lane & 15;
    const int oct   = lane >> 4;    // k-octet; frags valid for oct<2 (k<16)
    const bool actv = (lane < 32);

    // Stage B-slab features into LDS (512 pts x 32 B).
    {
        const unsigned short* gB = Bfeat + ((size_t)(batch * NPTS + bSlab * 512)) * 16;
        for (int c = t; c < 1024; c += 256) {
            const int pt = c >> 1, o = c & 1;
            *(float4*)&sB[((size_t)o * 512 + pt) * 8] = *(const float4*)&gB[(size_t)c * 8];
        }
    }

    // This wave's 8 A-fragments, straight from global (L2-resident).
    bf16x8 afr[8];
#pragma unroll
    for (int k = 0; k < 8; ++k) {
        bf16x8 v = (bf16x8)(short)0;
        if (actv) {
            const int pt = (aSlab * 32 + w * 8 + k) * 16 + col16;
            v = *(const bf16x8*)(Afeat + ((size_t)(batch * NPTS + pt)) * 16 + oct * 8);
        }
        afr[k] = v;
    }

    f32x4 vminA[8];
#pragma unroll
    for (int k = 0; k < 8; ++k) vminA[k] = (f32x4)(3.0e38f);

    __syncthreads();

    unsigned int* rowKey = keys + batch * NPTS;               // dir0: tpl -> src
    unsigned int* colKey = keys + BATCH * NPTS + batch * NPTS; // dir1: src -> tpl

    for (int bt = 0; bt < 32; ++bt) {
        bf16x8 bfr = (bf16x8)(short)0;
        if (actv)
            bfr = *(const bf16x8*)&sB[((size_t)oct * 512 + bt * 16 + col16) * 8];
        float cmin = 3.0e38f;
#pragma unroll
        for (int k = 0; k < 8; ++k) {
            f32x4 d = __builtin_amdgcn_mfma_f32_16x16x32_bf16(afr[k], bfr, (f32x4)(0.0f), 0, 0, 0);
            vminA[k][0] = fminf(vminA[k][0], d[0]);
            vminA[k][1] = fminf(vminA[k][1], d[1]);
            vminA[k][2] = fminf(vminA[k][2], d[2]);
            vminA[k][3] = fminf(vminA[k][3], d[3]);
            cmin = fminf(cmin, fminf(fminf(d[0], d[1]), fminf(d[2], d[3])));
        }
        // col-min over this wave's 128 rows: fold the 4 row-groups.
        cmin = fminf(cmin, __shfl_xor(cmin, 16));
        cmin = fminf(cmin, __shfl_xor(cmin, 32));
        if (lane < 16)
            atomicMin(&colKey[bSlab * 512 + bt * 16 + lane], fkey(cmin));
    }

    // Row mins: fold the 16 col-slots (lane&15), then merge globally.
#pragma unroll
    for (int k = 0; k < 8; ++k) {
#pragma unroll
        for (int r = 0; r < 4; ++r) {
            float v = vminA[k][r];
            v = fminf(v, __shfl_xor(v, 1));
            v = fminf(v, __shfl_xor(v, 2));
            v = fminf(v, __shfl_xor(v, 4));
            v = fminf(v, __shfl_xor(v, 8));
            if (col16 == 0) {
                const int row = (aSlab * 32 + w * 8 + k) * 16 + (lane >> 4) * 4 + r;
                atomicMin(&rowKey[row], fkey(v));
            }
        }
    }
}

// Decode key, sqrt(max(d2,1e-12)), per-block deterministic sums.
__global__ __launch_bounds__(256) void reduce_rows_kernel(
    const unsigned int* __restrict__ minkey, float* __restrict__ blockSums)
{
    const int gid = blockIdx.x * 256 + threadIdx.x;
    const float v = funkey(minkey[gid]);
    float d = sqrtf(fmaxf(v, 1e-12f));
#pragma unroll
    for (int off = 32; off; off >>= 1) d += __shfl_down(d, off);
    __shared__ float wsum[4];
    const int wave = threadIdx.x >> 6, lane = threadIdx.x & 63;
    if (lane == 0) wsum[wave] = d;
    __syncthreads();
    if (threadIdx.x == 0)
        blockSums[blockIdx.x] = (wsum[0] + wsum[1]) + (wsum[2] + wsum[3]);
}

__global__ __launch_bounds__(256) void final_kernel(
    const float* __restrict__ blockSums, float* __restrict__ out)
{
    float d = blockSums[threadIdx.x];
#pragma unroll
    for (int off = 32; off; off >>= 1) d += __shfl_down(d, off);
    __shared__ float wsum[4];
    const int wave = threadIdx.x >> 6, lane = threadIdx.x & 63;
    if (lane == 0) wsum[wave] = d;
    __syncthreads();
    if (threadIdx.x == 0) {
        const float total = (wsum[0] + wsum[1]) + (wsum[2] + wsum[3]);
        out[0] = total / (float)(BATCH * NPTS);
    }
}

extern "C" void kernel_launch(void* const* d_in, const int* in_sizes, int n_in,
                              void* d_out, int out_size, void* d_ws, size_t ws_size,
                              hipStream_t stream) {
    const float* tpl = (const float*)d_in[0];
    const float* src = (const float*)d_in[1];
    float* out = (float*)d_out;

    unsigned short* Afeat = (unsigned short*)d_ws;                       // 1 MB
    unsigned short* Bfeat = (unsigned short*)d_ws + (size_t)BATCH * NPTS * 16; // 1 MB
    unsigned int* keys    = (unsigned int*)((char*)d_ws + 2u * 1024 * 1024);   // 256 KB
    float* blockSums      = (float*)(keys + TOTAL_ROWS);

    hipMemsetAsync(keys, 0xFF, (size_t)TOTAL_ROWS * sizeof(unsigned int), stream);

    prep_kernel<<<TOTAL_ROWS / 256, 256, 0, stream>>>(tpl, src, Afeat, Bfeat);

    dim3 grid(NPTS / 512, NPTS / 512, BATCH);   // (16, 16, 4)
    chamfer_mfma_kernel<<<grid, 256, 0, stream>>>(Afeat, Bfeat, keys);

    reduce_rows_kernel<<<TOTAL_ROWS / 256, 256, 0, stream>>>(keys, blockSums);
    final_kernel<<<1, 256, 0, stream>>>(blockSums, out);
}

// Round 4
// 48.609 us; speedup vs baseline: 1.3672x; 1.3672x over previous
//
#include <hip/hip_runtime.h>

#define BATCH 4
#define NPTS 8192
#define TOTAL_ROWS (2 * BATCH * NPTS)   // 65536 min-keys (dir0 rows + dir1 cols)

typedef __attribute__((ext_vector_type(8))) short bf16x8;
typedef __attribute__((ext_vector_type(16))) float f32x16;

// Monotone float<->uint key: unsigned ascending == float ascending.
__device__ __forceinline__ unsigned fkey(float f) {
    unsigned u = __float_as_uint(f);
    return (u & 0x80000000u) ? ~u : (u | 0x80000000u);
}
__device__ __forceinline__ float funkey(unsigned k) {
    return (k & 0x80000000u) ? __uint_as_float(k ^ 0x80000000u) : __uint_as_float(~k);
}
__device__ __forceinline__ unsigned short bf16rn(float f) {
    unsigned u = __float_as_uint(f);
    return (unsigned short)((u + 0x7FFFu + ((u >> 16) & 1u)) >> 16);
}
__device__ __forceinline__ float bf2f(unsigned short h) {
    return __uint_as_float(((unsigned)h) << 16);
}

// Feature K-slot pairing (A[k]*B[k] summed by MFMA, K=16 of 32x32x16):
//  k0-2 : (-2a)_h * b_h      k3-5 : (-2a)_l * b_h     k6-8 : (-2a)_h * b_l
//  k9-10: a2_h,a2_l * 1      k11-12: 1 * b2_h,b2_l    k13-15: 0
// => D[m,n] = a^2 + b^2 - 2 a.b  (drops only (-2a)_l*b_l ~ 2^-18)
// Also initializes the min-key array (replaces a memset dispatch).
__global__ __launch_bounds__(256) void prep_kernel(
    const float* __restrict__ tpl, const float* __restrict__ src,
    unsigned short* __restrict__ Afeat, unsigned short* __restrict__ Bfeat,
    unsigned int* __restrict__ keys)
{
    const int gid = blockIdx.x * 256 + threadIdx.x;   // 0..65535
    keys[gid] = 0xFFFFFFFFu;

    const int which = gid >> 15;                       // 0: tpl (A-side), 1: src (B-side)
    const int idx = gid & 32767;                       // batch*NPTS + pt
    const float* p = (which ? src : tpl) + (size_t)idx * 3;
    const float x = p[0], y = p[1], z = p[2];
    const float n2 = fmaf(x, x, fmaf(y, y, z * z));
    const unsigned short n2h = bf16rn(n2);
    const unsigned short n2l = bf16rn(n2 - bf2f(n2h));
    const unsigned short ONE = 0x3F80;

    __attribute__((aligned(16))) unsigned short f[16];
    if (which == 0) {
        const float mx = -2.0f * x, my = -2.0f * y, mz = -2.0f * z;
        const unsigned short hx = bf16rn(mx), hy = bf16rn(my), hz = bf16rn(mz);
        const unsigned short lx = bf16rn(mx - bf2f(hx));
        const unsigned short ly = bf16rn(my - bf2f(hy));
        const unsigned short lz = bf16rn(mz - bf2f(hz));
        f[0]=hx; f[1]=hy; f[2]=hz; f[3]=lx; f[4]=ly; f[5]=lz;
        f[6]=hx; f[7]=hy; f[8]=hz; f[9]=n2h; f[10]=n2l; f[11]=ONE; f[12]=ONE;
        f[13]=0; f[14]=0; f[15]=0;
        unsigned short* o = Afeat + (size_t)idx * 16;
        *(float4*)&o[0] = *(float4*)&f[0];
        *(float4*)&o[8] = *(float4*)&f[8];
    } else {
        const unsigned short hx = bf16rn(x), hy = bf16rn(y), hz = bf16rn(z);
        const unsigned short lx = bf16rn(x - bf2f(hx));
        const unsigned short ly = bf16rn(y - bf2f(hy));
        const unsigned short lz = bf16rn(z - bf2f(hz));
        f[0]=hx; f[1]=hy; f[2]=hz; f[3]=hx; f[4]=hy; f[5]=hz;
        f[6]=lx; f[7]=ly; f[8]=lz; f[9]=ONE; f[10]=ONE; f[11]=n2h; f[12]=n2l;
        f[13]=0; f[14]=0; f[15]=0;
        unsigned short* o = Bfeat + (size_t)idx * 16;
        *(float4*)&o[0] = *(float4*)&f[0];
        *(float4*)&o[8] = *(float4*)&f[8];
    }
}

// Main kernel: block = (a-slab 256 rows) x (b-slab 512 cols) x batch.
// 4 waves, each owning 64 rows (2 MFMA row-tiles of 32), iterating 16 b-tiles.
// Shared distance matrix serves both directions:
//   row-min (tpl->src) in registers; col-min (src->tpl) folded via LDS atomics.
// Global atomics only at block end (~768 per block).
// 32x32x16 layouts: A row=lane&31, k=(lane>>5)*8+j; B col=lane&31, same k.
// C/D: col=lane&31, row=(r&3)+8*(r>>2)+4*(lane>>5)   [HW-verified mapping]
__global__ __launch_bounds__(256, 4) void chamfer_mfma_kernel(
    const unsigned short* __restrict__ Afeat,
    const unsigned short* __restrict__ Bfeat,
    unsigned int* __restrict__ keys)
{
    __shared__ __align__(16) unsigned short sB[2 * 512 * 8];   // 16 KB [half][pt][8]
    __shared__ unsigned int colminLDS[512];                    // 2 KB

    const int aSlab = blockIdx.x;   // 0..31 (256 rows)
    const int bSlab = blockIdx.y;   // 0..15 (512 cols)
    const int batch = blockIdx.z;   // 0..3

    const int t    = threadIdx.x;
    const int w    = t >> 6;        // wave 0..3
    const int lane = t & 63;
    const int col  = lane & 31;
    const int half = lane >> 5;     // k-half (k0-7 / k8-15)

    for (int i = t; i < 512; i += 256) colminLDS[i] = 0xFFFFFFFFu;

    // Stage B-slab features (512 pts x 32 B) into LDS, split by k-half.
    {
        const float4* gB = (const float4*)(Bfeat + ((size_t)(batch * NPTS + bSlab * 512)) * 16);
        for (int c = t; c < 1024; c += 256) {
            const int pt = c >> 1, h = c & 1;
            *(float4*)&sB[((size_t)(h * 512 + pt)) * 8] = gB[c];
        }
    }

    // This wave's 2 A-fragments (64 rows), straight from global (L2-resident).
    const unsigned short* gA = Afeat + ((size_t)(batch * NPTS + aSlab * 256)) * 16;
    bf16x8 afr[2];
#pragma unroll
    for (int a = 0; a < 2; ++a)
        afr[a] = *(const bf16x8*)(gA + ((size_t)(w * 64 + a * 32 + col)) * 16 + half * 8);

    float vmin[2][16];
#pragma unroll
    for (int a = 0; a < 2; ++a)
#pragma unroll
        for (int r = 0; r < 16; ++r) vmin[a][r] = 3.0e38f;

    const f32x16 ZERO = (f32x16)(0.0f);

    __syncthreads();

#pragma unroll 2
    for (int bt = 0; bt < 16; ++bt) {
        const bf16x8 bfr = *(const bf16x8*)&sB[((size_t)(half * 512 + bt * 32 + col)) * 8];
        float cmin = 3.0e38f;
#pragma unroll
        for (int a = 0; a < 2; ++a) {
            const f32x16 d = __builtin_amdgcn_mfma_f32_32x32x16_bf16(afr[a], bfr, ZERO, 0, 0, 0);
#pragma unroll
            for (int r = 0; r < 16; ++r) vmin[a][r] = fminf(vmin[a][r], d[r]);
            const float t0 = fminf(fminf(d[0], d[1]), fminf(d[2], d[3]));
            const float t1 = fminf(fminf(d[4], d[5]), fminf(d[6], d[7]));
            const float t2 = fminf(fminf(d[8], d[9]), fminf(d[10], d[11]));
            const float t3 = fminf(fminf(d[12], d[13]), fminf(d[14], d[15]));
            cmin = fminf(cmin, fminf(fminf(t0, t1), fminf(t2, t3)));
        }
        // fold the two k-halves (complementary 16-row sets) -> 64-row col-min
        cmin = fminf(cmin, __shfl_xor(cmin, 32));
        if (lane < 32) atomicMin(&colminLDS[bt * 32 + col], fkey(cmin));  // LDS atomic
    }
    __syncthreads();

    unsigned int* rowKey = keys + batch * NPTS;                 // dir0: tpl -> src
    unsigned int* colKey = keys + BATCH * NPTS + batch * NPTS;  // dir1: src -> tpl

    // Col write-out: one global atomic per col per block.
    for (int i = t; i < 512; i += 256)
        atomicMin(&colKey[bSlab * 512 + i], colminLDS[i]);

    // Row mins: fold across the 32 col-lanes (bits 0-4; halves hold distinct rows).
#pragma unroll
    for (int a = 0; a < 2; ++a) {
#pragma unroll
        for (int r = 0; r < 16; ++r) {
            float v = vmin[a][r];
            v = fminf(v, __shfl_xor(v, 1));
            v = fminf(v, __shfl_xor(v, 2));
            v = fminf(v, __shfl_xor(v, 4));
            v = fminf(v, __shfl_xor(v, 8));
            v = fminf(v, __shfl_xor(v, 16));
            if (col == 0) {
                const int row = aSlab * 256 + w * 64 + a * 32 + (r & 3) + 8 * (r >> 2) + 4 * half;
                atomicMin(&rowKey[row], fkey(v));
            }
        }
    }
}

// Decode key, sqrt(max(d2,1e-12)), per-block deterministic sums.
__global__ __launch_bounds__(256) void reduce_rows_kernel(
    const unsigned int* __restrict__ minkey, float* __restrict__ blockSums)
{
    const int gid = blockIdx.x * 256 + threadIdx.x;
    const float v = funkey(minkey[gid]);
    float d = sqrtf(fmaxf(v, 1e-12f));
#pragma unroll
    for (int off = 32; off; off >>= 1) d += __shfl_down(d, off);
    __shared__ float wsum[4];
    const int wave = threadIdx.x >> 6, lane = threadIdx.x & 63;
    if (lane == 0) wsum[wave] = d;
    __syncthreads();
    if (threadIdx.x == 0)
        blockSums[blockIdx.x] = (wsum[0] + wsum[1]) + (wsum[2] + wsum[3]);
}

__global__ __launch_bounds__(256) void final_kernel(
    const float* __restrict__ blockSums, float* __restrict__ out)
{
    float d = blockSums[threadIdx.x];
#pragma unroll
    for (int off = 32; off; off >>= 1) d += __shfl_down(d, off);
    __shared__ float wsum[4];
    const int wave = threadIdx.x >> 6, lane = threadIdx.x & 63;
    if (lane == 0) wsum[wave] = d;
    __syncthreads();
    if (threadIdx.x == 0) {
        const float total = (wsum[0] + wsum[1]) + (wsum[2] + wsum[3]);
        out[0] = total / (float)(BATCH * NPTS);
    }
}

extern "C" void kernel_launch(void* const* d_in, const int* in_sizes, int n_in,
                              void* d_out, int out_size, void* d_ws, size_t ws_size,
                              hipStream_t stream) {
    const float* tpl = (const float*)d_in[0];
    const float* src = (const float*)d_in[1];
    float* out = (float*)d_out;

    unsigned short* Afeat = (unsigned short*)d_ws;                             // 1 MB
    unsigned short* Bfeat = (unsigned short*)d_ws + (size_t)BATCH * NPTS * 16; // 1 MB
    unsigned int* keys    = (unsigned int*)((char*)d_ws + 2u * 1024 * 1024);   // 256 KB
    float* blockSums      = (float*)(keys + TOTAL_ROWS);

    prep_kernel<<<TOTAL_ROWS / 256, 256, 0, stream>>>(tpl, src, Afeat, Bfeat, keys);

    dim3 grid(NPTS / 256, NPTS / 512, BATCH);   // (32, 16, 4) = 2048 blocks
    chamfer_mfma_kernel<<<grid, 256, 0, stream>>>(Afeat, Bfeat, keys);

    reduce_rows_kernel<<<TOTAL_ROWS / 256, 256, 0, stream>>>(keys, blockSums);
    final_kernel<<<1, 256, 0, stream>>>(blockSums, out);
}